// Round 12
// baseline (79.425 us; speedup 1.0000x reference)
//
#include <hip/hip_runtime.h>
#include <math.h>

#define NB 32
#define NN 10000
#define DIM 256
#define NH 16
#define NPART 24          // 32*24 = 768 blocks = exactly 3/CU at 3 blk/CU
#define PREC2 4112        // per-block partial: l[16] + g[16*256]
#define IDXSTRIDE 10240

typedef short short8v __attribute__((ext_vector_type(8)));
typedef float float4v __attribute__((ext_vector_type(4)));

// ---- bf16 helpers (RNE pack) ----
__device__ __forceinline__ unsigned bf16rne(float f) {
    unsigned u = __float_as_uint(f);
    return (u + 0x7FFFu + ((u >> 16) & 1u)) >> 16;
}
__device__ __forceinline__ unsigned pack2(float a, float b) {
    return bf16rne(a) | (bf16rne(b) << 16);
}
__device__ __forceinline__ short8v pack8(float4 A, float4 B) {
    union { short8v s; unsigned u[4]; } r;
    r.u[0] = pack2(A.x, A.y); r.u[1] = pack2(A.z, A.w);
    r.u[2] = pack2(B.x, B.y); r.u[3] = pack2(B.z, B.w);
    return r.s;
}
// row-parity XOR swizzle for XT (128B rows)
#define SWB(d) ((((d) >> 1) & 7) << 4)

// ---------------- kernel 1: prep (blocks 0..127) + compact (128..159) -------
__global__ void prep_compact_kernel(const float* __restrict__ ctx,
                                    const float* __restrict__ Wq,
                                    const float* __restrict__ Wk,
                                    const void* __restrict__ maskp,
                                    float* __restrict__ wt,
                                    int* __restrict__ idx,
                                    int* __restrict__ cnt) {
    int bid = blockIdx.x;
    int t = threadIdx.x, lane = t & 63, w = t >> 6;

    __shared__ float ctxL[DIM];
    __shared__ float qL[64];
    __shared__ int sflag;
    __shared__ int wcnt[4];

    if (bid < 4 * NB) {
        // ---------------- prep: q then w~ ----------------
        int b = bid >> 2, iq = bid & 3;
        ctxL[t] = ctx[b * DIM + t];
        __syncthreads();

        float4 c = ((const float4*)ctxL)[lane];
        for (int i = iq * 64 + w; i < iq * 64 + 64; i += 4) {
            float4 wq = ((const float4*)(Wq + (size_t)i * DIM))[lane];
            float s = wq.x * c.x + wq.y * c.y + wq.z * c.z + wq.w * c.w;
            #pragma unroll
            for (int off = 1; off < 64; off <<= 1) s += __shfl_xor(s, off, 64);
            if (lane == 0) qL[i - iq * 64] = s;
        }
        __syncthreads();

        #pragma unroll
        for (int hh = 0; hh < 4; ++hh) {
            int h = iq * 4 + hh;
            float a = 0.f;
            #pragma unroll
            for (int j = 0; j < 16; ++j)
                a += qL[hh * 16 + j] * Wk[(size_t)(h * 16 + j) * DIM + t];
            wt[((size_t)b * NH + h) * DIM + t] = 0.25f * a;
        }
    } else {
        // ---------------- compact (stable, per-wave segments) --------------
        int b = bid - 4 * NB;
        const int* wordbase = (const int*)maskp + (size_t)b * (NN / 4);
        int bad = 0;
        for (int i = t; i < NN / 4; i += 256)
            if ((unsigned)wordbase[i] > 1u) bad = 1;
        if (t == 0) sflag = 0;
        __syncthreads();
        if (bad) sflag = 1;            // benign race: same value
        __syncthreads();
        const bool bytemask = (sflag != 0);
        const unsigned char* m8 = (const unsigned char*)maskp + (size_t)b * NN;
        const int* m32 = (const int*)maskp + (size_t)b * NN;

        int segbeg = w * (NN / 4);
        int segend = segbeg + (NN / 4);

        int c1 = 0;
        for (int base = segbeg; base < segend; base += 64) {
            int i = base + lane;
            int pred = (i < segend) ? (bytemask ? (m8[i] != 0) : (m32[i] != 0)) : 0;
            unsigned long long bal = __ballot(pred);
            c1 += __popcll(bal);
        }
        if (lane == 0) wcnt[w] = c1;
        __syncthreads();

        int run = 0;
        for (int k = 0; k < w; ++k) run += wcnt[k];

        int* ob = idx + (size_t)b * IDXSTRIDE;
        for (int base = segbeg; base < segend; base += 64) {
            int i = base + lane;
            int pred = (i < segend) ? (bytemask ? (m8[i] != 0) : (m32[i] != 0)) : 0;
            unsigned long long bal = __ballot(pred);
            int rank = __popcll(bal & ((1ull << lane) - 1ull));
            if (pred) ob[run + rank] = i;
            run += __popcll(bal);
        }
        if (t == 0) cnt[b] = wcnt[0] + wcnt[1] + wcnt[2] + wcnt[3];
    }
}

// ---------------- kernel 2: MFMA attend, MLP-explicit phase A ---------------
// Per 64-node tile:
//  phase A (wave = 16 compacted rows): issue ALL 16 row loads first
//    (sched_group_barrier pins them ahead) -> 15 loads stay in flight while
//    pack/scatter/MFMA consume them in order. Then p = exp(S), P -> PL.
//  phase B (wave = 64 d-cols): G^T += X^T . P^T via 8x MFMA from XT/PL.
__launch_bounds__(256, 3)
__global__ void attend_kernel(const float* __restrict__ node,
                              const int* __restrict__ idx,
                              const int* __restrict__ cntarr,
                              const float* __restrict__ wt,
                              float* __restrict__ partials) {
    __shared__ __align__(16) char smem[35328];  // XT 32768 | PL 2304 | LL 256
    char* XT = smem;
    char* PL = smem + 32768;
    float* LL = (float*)(smem + 35072);

    int b = blockIdx.x / NPART;
    int part = blockIdx.x % NPART;
    int t = threadIdx.x, lane = t & 63;
    int w = __builtin_amdgcn_readfirstlane(t >> 6);
    int hq = lane & 15, g = lane >> 4;

    int cnt = cntarr[b];
    int psz = ((cnt + NPART * 64 - 1) / (NPART * 64)) * 64;  // tile-aligned
    int n0 = part * psz;
    int n1 = n0 + psz; if (n1 > cnt) n1 = cnt;

    const float* nb = node + (size_t)b * NN * DIM;
    const int* ib = idx + (size_t)b * IDXSTRIDE;

    // hoist w~ B-fragments (once per block; same for all waves)
    short8v wfrag0, wfrag1, wfrag2, wfrag3, wfrag4, wfrag5, wfrag6, wfrag7;
    {
        const float* wrow = wt + ((size_t)b * NH + hq) * DIM + g * 8;
        #define WLOAD(cc) wfrag##cc = pack8(*(const float4*)(wrow + cc * 32), \
                                            *(const float4*)(wrow + cc * 32 + 4));
        WLOAD(0) WLOAD(1) WLOAD(2) WLOAD(3) WLOAD(4) WLOAD(5) WLOAD(6) WLOAD(7)
        #undef WLOAD
    }

    float4v accB0 = (float4v){0.f,0.f,0.f,0.f};
    float4v accB1 = accB0, accB2 = accB0, accB3 = accB0;
    float lacc = 0.f;
    int ln2 = (16 * w + hq) * 2;   // XT byte-column of this lane's node slot

    for (int tb = n0; tb < n1; tb += 64) {
        __syncthreads();   // prev phase B done: XT/PL reusable

        // ---- phase A: ALL 16 loads first (MLP), then pack/scatter/MFMA ----
        float4v acc = (float4v){0.f, 0.f, 0.f, 0.f};
        {
            int pos = tb + 16 * w + hq;
            if (pos > cnt - 1) pos = cnt - 1;    // pad lanes: killed by position gate
            int ni = ib[pos];
            const float* arow = nb + (size_t)ni * DIM + g * 8;
            float4 A0 = *(const float4*)(arow + 0),   B0 = *(const float4*)(arow + 4);
            float4 A1 = *(const float4*)(arow + 32),  B1 = *(const float4*)(arow + 36);
            float4 A2 = *(const float4*)(arow + 64),  B2 = *(const float4*)(arow + 68);
            float4 A3 = *(const float4*)(arow + 96),  B3 = *(const float4*)(arow + 100);
            float4 A4 = *(const float4*)(arow + 128), B4 = *(const float4*)(arow + 132);
            float4 A5 = *(const float4*)(arow + 160), B5 = *(const float4*)(arow + 164);
            float4 A6 = *(const float4*)(arow + 192), B6 = *(const float4*)(arow + 196);
            float4 A7 = *(const float4*)(arow + 224), B7 = *(const float4*)(arow + 228);
            // pin: 16 VMEM reads scheduled before anything below
            __builtin_amdgcn_sched_group_barrier(0x20, 16, 0);

            #define STEP_A(cc) { \
                short8v af = pack8(A##cc, B##cc); \
                union { short8v s; unsigned short u[8]; } U; U.s = af; \
                int d0 = g * 8 + cc * 32; \
                _Pragma("unroll") \
                for (int j = 0; j < 8; ++j) \
                    *(unsigned short*)(XT + (size_t)(d0 + j) * 128 + \
                                       (ln2 ^ SWB(d0 + j))) = U.u[j]; \
                acc = __builtin_amdgcn_mfma_f32_16x16x32_bf16(af, wfrag##cc, acc, 0, 0, 0); \
            }
            STEP_A(0) STEP_A(1) STEP_A(2) STEP_A(3)
            STEP_A(4) STEP_A(5) STEP_A(6) STEP_A(7)
            #undef STEP_A
        }

        // position gate replaces the mask (compacted rows are all feasible);
        // logits ~N(0,1): exp safe in fp32
        int mb_ = tb + 16 * w + 4 * g;
        float p0 = (mb_ + 0 < n1) ? __expf(acc[0]) : 0.f;
        float p1 = (mb_ + 1 < n1) ? __expf(acc[1]) : 0.f;
        float p2 = (mb_ + 2 < n1) ? __expf(acc[2]) : 0.f;
        float p3 = (mb_ + 3 < n1) ? __expf(acc[3]) : 0.f;
        float ts = p0 + p1 + p2 + p3;
        ts += __shfl_xor(ts, 16, 64);
        ts += __shfl_xor(ts, 32, 64);
        lacc += ts;
        *(uint2*)(PL + hq * 144 + (16 * w + 4 * g) * 2) =
            make_uint2(pack2(p0, p1), pack2(p2, p3));

        __syncthreads();   // XT + PL ready

        // ---- phase B: G^T[d][h] += X^T . P^T ; wave owns d = 64w..64w+63 ----
        #pragma unroll
        for (int chunk = 0; chunk < 2; ++chunk) {
            short8v pf = *(const short8v*)(PL + hq * 144 + chunk * 64 + g * 16);
            int d0 = 64 * w + hq;
            short8v xf0 = *(const short8v*)(XT + (size_t)(d0) * 128 +
                                            ((chunk * 64 + g * 16) ^ SWB(d0)));
            short8v xf1 = *(const short8v*)(XT + (size_t)(d0 + 16) * 128 +
                                            ((chunk * 64 + g * 16) ^ SWB(d0 + 16)));
            short8v xf2 = *(const short8v*)(XT + (size_t)(d0 + 32) * 128 +
                                            ((chunk * 64 + g * 16) ^ SWB(d0 + 32)));
            short8v xf3 = *(const short8v*)(XT + (size_t)(d0 + 48) * 128 +
                                            ((chunk * 64 + g * 16) ^ SWB(d0 + 48)));
            accB0 = __builtin_amdgcn_mfma_f32_16x16x32_bf16(xf0, pf, accB0, 0, 0, 0);
            accB1 = __builtin_amdgcn_mfma_f32_16x16x32_bf16(xf1, pf, accB1, 0, 0, 0);
            accB2 = __builtin_amdgcn_mfma_f32_16x16x32_bf16(xf2, pf, accB2, 0, 0, 0);
            accB3 = __builtin_amdgcn_mfma_f32_16x16x32_bf16(xf3, pf, accB3, 0, 0, 0);
        }
    }

    // ---- epilogue: bounce G through LDS for coalesced partial write ----
    __syncthreads();
    float* GL = (float*)smem;                      // [16][260] f32, reuses XT
    #pragma unroll
    for (int r = 0; r < 4; ++r) {
        GL[hq * 260 + 64 * w +  0 + 4 * g + r] = accB0[r];
        GL[hq * 260 + 64 * w + 16 + 4 * g + r] = accB1[r];
        GL[hq * 260 + 64 * w + 32 + 4 * g + r] = accB2[r];
        GL[hq * 260 + 64 * w + 48 + 4 * g + r] = accB3[r];
    }
    if (lane < 16) LL[w * 16 + lane] = lacc;
    __syncthreads();

    float* rec = partials + (size_t)blockIdx.x * PREC2;
    if (t < NH) rec[t] = LL[t] + LL[16 + t] + LL[32 + t] + LL[48 + t];
    for (int i = t; i < NH * DIM; i += 256)
        rec[16 + i] = GL[(i >> 8) * 260 + (i & 255)];
}

// ---------------- kernel 3: merge partials + hc (fused) ---------------------
__global__ void reduce_hc_kernel(const float* __restrict__ partials,
                                 const float* __restrict__ Wv,
                                 float* __restrict__ hcws) {
    int b = blockIdx.x >> 4, h = blockIdx.x & 15;
    int t = threadIdx.x;
    __shared__ float grow[DIM];
    __shared__ float lp[NPART];
    __shared__ float lsum;

    const float* pb = partials + (size_t)b * NPART * PREC2;
    float a = 0.f;
    for (int p = 0; p < NPART; ++p) a += pb[(size_t)p * PREC2 + 16 + h * DIM + t];
    grow[t] = a;
    if (t < NPART) lp[t] = pb[(size_t)t * PREC2 + h];
    __syncthreads();
    if (t == 0) {
        float s = 0.f;
        #pragma unroll
        for (int p = 0; p < NPART; ++p) s += lp[p];
        lsum = s;
    }
    __syncthreads();

    int i = h * 16 + (t >> 4), sub = t & 15;
    const float4* wrow = (const float4*)(Wv + (size_t)i * DIM + sub * 16);
    const float4* gr = (const float4*)(grow + sub * 16);
    float s = 0.f;
    #pragma unroll
    for (int k = 0; k < 4; ++k) {
        float4 wv = wrow[k], gv = gr[k];
        s += wv.x * gv.x + wv.y * gv.y + wv.z * gv.z + wv.w * gv.w;
    }
    s += __shfl_xor(s, 1, 64);
    s += __shfl_xor(s, 2, 64);
    s += __shfl_xor(s, 4, 64);
    s += __shfl_xor(s, 8, 64);
    if (sub == 0) hcws[(size_t)b * DIM + i] = s / lsum;
}

// ---------------- kernel 4: out[b,e] = dot(hc[b,:], Wo[e,:]) ----------------
__global__ void out_kernel(const float* __restrict__ hcws,
                           const float* __restrict__ Wo,
                           float* __restrict__ out) {
    int b = blockIdx.x >> 3, o = blockIdx.x & 7;
    int t = threadIdx.x;
    int e = o * 32 + (t >> 3), sub = t & 7;
    const float4* wrow = (const float4*)(Wo + (size_t)e * DIM + sub * 32);
    const float4* hrow = (const float4*)(hcws + (size_t)b * DIM + sub * 32);
    float a = 0.f;
    #pragma unroll
    for (int k = 0; k < 8; ++k) {
        float4 wv = wrow[k], hv = hrow[k];
        a += wv.x * hv.x + wv.y * hv.y + wv.z * hv.z + wv.w * hv.w;
    }
    a += __shfl_xor(a, 1, 64);
    a += __shfl_xor(a, 2, 64);
    a += __shfl_xor(a, 4, 64);
    if (sub == 0) out[(size_t)b * DIM + e] = a;
}

extern "C" void kernel_launch(void* const* d_in, const int* in_sizes, int n_in,
                              void* d_out, int out_size, void* d_ws, size_t ws_size,
                              hipStream_t stream) {
    const float* ctx  = (const float*)d_in[0];
    const float* node = (const float*)d_in[1];
    const void*  mask = (const void*)d_in[2];
    const float* Wq   = (const float*)d_in[3];
    const float* Wk   = (const float*)d_in[4];
    const float* Wv   = (const float*)d_in[5];
    const float* Wo   = (const float*)d_in[6];
    float* out = (float*)d_out;

    // ws floats: wt 131072 | hcws 8192 | cnt 256 | idx 32*10240 |
    //            partials 32*24*4112 (~12.6MB)
    float* wsf = (float*)d_ws;
    float* wt = wsf;
    float* hcws = wt + (size_t)NB * NH * DIM;
    int*   cnt = (int*)(hcws + (size_t)NB * DIM);
    int*   idx = cnt + 256;
    float* partials = (float*)(idx + (size_t)NB * IDXSTRIDE);

    prep_compact_kernel<<<NB * 4 + NB, 256, 0, stream>>>(ctx, Wq, Wk, mask, wt, idx, cnt);
    attend_kernel<<<NB * NPART, 256, 0, stream>>>(node, idx, cnt, wt, partials);
    reduce_hc_kernel<<<NB * 16, 256, 0, stream>>>(partials, Wv, hcws);
    out_kernel<<<NB * 8, 256, 0, stream>>>(hcws, Wo, out);
}

// Round 15
// 72.341 us; speedup vs baseline: 1.0979x; 1.0979x over previous
//
#include <hip/hip_runtime.h>
#include <math.h>

#define NB 32
#define NN 10000
#define DIM 256
#define NH 16
#define NPART 16          // 32*16 = 512 blocks = exactly 2/CU at 2 blk/CU
#define PREC2 4112        // per-block partial: l[16] + g[16*256]
#define IDXSTRIDE 10240

typedef short short8v __attribute__((ext_vector_type(8)));
typedef float float4v __attribute__((ext_vector_type(4)));

// ---- bf16 helpers (RNE pack) ----
__device__ __forceinline__ unsigned bf16rne(float f) {
    unsigned u = __float_as_uint(f);
    return (u + 0x7FFFu + ((u >> 16) & 1u)) >> 16;
}
__device__ __forceinline__ unsigned pack2(float a, float b) {
    return bf16rne(a) | (bf16rne(b) << 16);
}
__device__ __forceinline__ short8v pack8(float4 A, float4 B) {
    union { short8v s; unsigned u[4]; } r;
    r.u[0] = pack2(A.x, A.y); r.u[1] = pack2(A.z, A.w);
    r.u[2] = pack2(B.x, B.y); r.u[3] = pack2(B.z, B.w);
    return r.s;
}
// row-parity XOR swizzle for XT (128B rows)
#define SWB(d) ((((d) >> 1) & 7) << 4)

// ---------------- kernel 1: prep (blocks 0..127) + compact (128..159) -------
__global__ void prep_compact_kernel(const float* __restrict__ ctx,
                                    const float* __restrict__ Wq,
                                    const float* __restrict__ Wk,
                                    const void* __restrict__ maskp,
                                    float* __restrict__ wt,
                                    int* __restrict__ idx,
                                    int* __restrict__ cnt) {
    int bid = blockIdx.x;
    int t = threadIdx.x, lane = t & 63, w = t >> 6;

    __shared__ float ctxL[DIM];
    __shared__ float qL[64];
    __shared__ int sflag;
    __shared__ int wcnt[4];

    if (bid < 4 * NB) {
        // ---------------- prep: q then w~ ----------------
        int b = bid >> 2, iq = bid & 3;
        ctxL[t] = ctx[b * DIM + t];
        __syncthreads();

        float4 c = ((const float4*)ctxL)[lane];
        for (int i = iq * 64 + w; i < iq * 64 + 64; i += 4) {
            float4 wq = ((const float4*)(Wq + (size_t)i * DIM))[lane];
            float s = wq.x * c.x + wq.y * c.y + wq.z * c.z + wq.w * c.w;
            #pragma unroll
            for (int off = 1; off < 64; off <<= 1) s += __shfl_xor(s, off, 64);
            if (lane == 0) qL[i - iq * 64] = s;
        }
        __syncthreads();

        #pragma unroll
        for (int hh = 0; hh < 4; ++hh) {
            int h = iq * 4 + hh;
            float a = 0.f;
            #pragma unroll
            for (int j = 0; j < 16; ++j)
                a += qL[hh * 16 + j] * Wk[(size_t)(h * 16 + j) * DIM + t];
            wt[((size_t)b * NH + h) * DIM + t] = 0.25f * a;
        }
    } else {
        // ---------------- compact (stable, per-wave segments) --------------
        int b = bid - 4 * NB;
        const int* wordbase = (const int*)maskp + (size_t)b * (NN / 4);
        int bad = 0;
        for (int i = t; i < NN / 4; i += 256)
            if ((unsigned)wordbase[i] > 1u) bad = 1;
        if (t == 0) sflag = 0;
        __syncthreads();
        if (bad) sflag = 1;            // benign race: same value
        __syncthreads();
        const bool bytemask = (sflag != 0);
        const unsigned char* m8 = (const unsigned char*)maskp + (size_t)b * NN;
        const int* m32 = (const int*)maskp + (size_t)b * NN;

        int segbeg = w * (NN / 4);
        int segend = segbeg + (NN / 4);

        int c1 = 0;
        for (int base = segbeg; base < segend; base += 64) {
            int i = base + lane;
            int pred = (i < segend) ? (bytemask ? (m8[i] != 0) : (m32[i] != 0)) : 0;
            unsigned long long bal = __ballot(pred);
            c1 += __popcll(bal);
        }
        if (lane == 0) wcnt[w] = c1;
        __syncthreads();

        int run = 0;
        for (int k = 0; k < w; ++k) run += wcnt[k];

        int* ob = idx + (size_t)b * IDXSTRIDE;
        for (int base = segbeg; base < segend; base += 64) {
            int i = base + lane;
            int pred = (i < segend) ? (bytemask ? (m8[i] != 0) : (m32[i] != 0)) : 0;
            unsigned long long bal = __ballot(pred);
            int rank = __popcll(bal & ((1ull << lane) - 1ull));
            if (pred) ob[run + rank] = i;
            run += __popcll(bal);
        }
        if (t == 0) cnt[b] = wcnt[0] + wcnt[1] + wcnt[2] + wcnt[3];
    }
}

// ---- file-scope macro pieces for the attend kernel (expand at use site) ----
// Buffer addresses are computed arithmetically from smem each time (no local
// pointer arrays -> no addrspacecast initializer, no scratch).
#define XTBUF(bb) (smem + (size_t)(bb) * 32768)
#define PLBUF(bb) (smem + 65536 + (size_t)(bb) * 2304)

// STEP_A: pack one 8-dword chunk, scatter into XTc, MFMA into acc.
#define STEP_A(cc) { \
    short8v af = pack8(LA##cc, LB##cc); \
    union { short8v s; unsigned short u[8]; } U; U.s = af; \
    int d0 = g * 8 + cc * 32; \
    _Pragma("unroll") \
    for (int j = 0; j < 8; ++j) \
        *(unsigned short*)(XTc + (size_t)(d0 + j) * 128 + \
                           (ln2 ^ SWB(d0 + j))) = U.u[j]; \
    acc = __builtin_amdgcn_mfma_f32_16x16x32_bf16(af, wfrag##cc, acc, 0, 0, 0); \
}

// PHASE_A_TAIL: full phase A for tile at tb_ into buffer cur_.
#define PHASE_A_TAIL(tb_, cur_) { \
    char* XTc = XTBUF(cur_); char* PLc = PLBUF(cur_); \
    float4v acc = (float4v){0.f, 0.f, 0.f, 0.f}; \
    STEP_A(0) STEP_A(1) STEP_A(2) STEP_A(3) \
    STEP_A(4) STEP_A(5) STEP_A(6) STEP_A(7) \
    int mb_ = (tb_) + 16 * w + 4 * g; \
    float p0 = (mb_ + 0 < n1) ? __expf(acc[0]) : 0.f; \
    float p1 = (mb_ + 1 < n1) ? __expf(acc[1]) : 0.f; \
    float p2 = (mb_ + 2 < n1) ? __expf(acc[2]) : 0.f; \
    float p3 = (mb_ + 3 < n1) ? __expf(acc[3]) : 0.f; \
    float ts = p0 + p1 + p2 + p3; \
    ts += __shfl_xor(ts, 16, 64); \
    ts += __shfl_xor(ts, 32, 64); \
    lacc += ts; \
    *(uint2*)(PLc + hq * 144 + (16 * w + 4 * g) * 2) = \
        make_uint2(pack2(p0, p1), pack2(p2, p3)); \
}

// PHASE_B: 8 MFMA + 10 ds_read_b128 consuming buffer bb.
#define PHASE_B(bb) { \
    char* XTp = XTBUF(bb); char* PLp = PLBUF(bb); \
    _Pragma("unroll") \
    for (int chunk = 0; chunk < 2; ++chunk) { \
        short8v pf = *(const short8v*)(PLp + hq * 144 + chunk * 64 + g * 16); \
        int d0 = 64 * w + hq; \
        short8v xf0 = *(const short8v*)(XTp + (size_t)(d0) * 128 + \
                                        ((chunk * 64 + g * 16) ^ SWB(d0))); \
        short8v xf1 = *(const short8v*)(XTp + (size_t)(d0 + 16) * 128 + \
                                        ((chunk * 64 + g * 16) ^ SWB(d0 + 16))); \
        short8v xf2 = *(const short8v*)(XTp + (size_t)(d0 + 32) * 128 + \
                                        ((chunk * 64 + g * 16) ^ SWB(d0 + 32))); \
        short8v xf3 = *(const short8v*)(XTp + (size_t)(d0 + 48) * 128 + \
                                        ((chunk * 64 + g * 16) ^ SWB(d0 + 48))); \
        accB0 = __builtin_amdgcn_mfma_f32_16x16x32_bf16(xf0, pf, accB0, 0, 0, 0); \
        accB1 = __builtin_amdgcn_mfma_f32_16x16x32_bf16(xf1, pf, accB1, 0, 0, 0); \
        accB2 = __builtin_amdgcn_mfma_f32_16x16x32_bf16(xf2, pf, accB2, 0, 0, 0); \
        accB3 = __builtin_amdgcn_mfma_f32_16x16x32_bf16(xf3, pf, accB3, 0, 0, 0); \
    } \
}

// LOAD_TILE: issue 16 row loads + next idx load as named scalars.
#define LOAD_TILE(nextpos_) \
    const float* arow = nb + (size_t)ni * DIM + g * 8; \
    float4 LA0 = *(const float4*)(arow + 0),   LB0 = *(const float4*)(arow + 4); \
    float4 LA1 = *(const float4*)(arow + 32),  LB1 = *(const float4*)(arow + 36); \
    float4 LA2 = *(const float4*)(arow + 64),  LB2 = *(const float4*)(arow + 68); \
    float4 LA3 = *(const float4*)(arow + 96),  LB3 = *(const float4*)(arow + 100); \
    float4 LA4 = *(const float4*)(arow + 128), LB4 = *(const float4*)(arow + 132); \
    float4 LA5 = *(const float4*)(arow + 160), LB5 = *(const float4*)(arow + 164); \
    float4 LA6 = *(const float4*)(arow + 192), LB6 = *(const float4*)(arow + 196); \
    float4 LA7 = *(const float4*)(arow + 224), LB7 = *(const float4*)(arow + 228); \
    int ni_next = ib[nextpos_]; \
    __builtin_amdgcn_sched_group_barrier(0x20, 17, 0);

// ---------------- kernel 2: MFMA attend, 1-barrier pipelined ----------------
// Double-buffered XT/PL. Segment k: issue tile-k row loads (+ idx prefetch)
// -> phase B of tile k-1 from the OTHER buffer (hides load latency)
// -> pack/scatter/MFMA A(k) (consumes loads) -> exp/PL -> ONE barrier.
// Loads are consumed before the barrier: registers never cross a barrier
// (no spill) and __syncthreads' vmcnt drain is free.
__launch_bounds__(256, 2)
__global__ void attend_kernel(const float* __restrict__ node,
                              const int* __restrict__ idx,
                              const int* __restrict__ cntarr,
                              const float* __restrict__ wt,
                              float* __restrict__ partials) {
    __shared__ __align__(16) char smem[70400];
    // layout: XT0 32768 | XT1 32768 | PL0 2304 | PL1 2304 | LL 256
    float* LL = (float*)(smem + 70144);

    int b = blockIdx.x / NPART;
    int part = blockIdx.x % NPART;
    int t = threadIdx.x, lane = t & 63;
    int w = __builtin_amdgcn_readfirstlane(t >> 6);
    int hq = lane & 15, g = lane >> 4;

    int cnt = cntarr[b];
    int psz = ((cnt + NPART * 64 - 1) / (NPART * 64)) * 64;  // tile-aligned
    int n0 = part * psz;
    int n1 = n0 + psz; if (n1 > cnt) n1 = cnt;

    const float* nb = node + (size_t)b * NN * DIM;
    const int* ib = idx + (size_t)b * IDXSTRIDE;

    // hoist w~ B-fragments (once per block; same for all waves)
    short8v wfrag0, wfrag1, wfrag2, wfrag3, wfrag4, wfrag5, wfrag6, wfrag7;
    {
        const float* wrow = wt + ((size_t)b * NH + hq) * DIM + g * 8;
        #define WLOAD(cc) wfrag##cc = pack8(*(const float4*)(wrow + cc * 32), \
                                            *(const float4*)(wrow + cc * 32 + 4));
        WLOAD(0) WLOAD(1) WLOAD(2) WLOAD(3) WLOAD(4) WLOAD(5) WLOAD(6) WLOAD(7)
        #undef WLOAD
    }

    float4v accB0 = (float4v){0.f,0.f,0.f,0.f};
    float4v accB1 = accB0, accB2 = accB0, accB3 = accB0;
    float lacc = 0.f;
    int ln2 = (16 * w + hq) * 2;   // XT byte-column of this lane's node slot
    int lastk = 0;

    if (n0 < n1) {
        // prologue: idx + loads for tile 0
        int pos = n0 + 16 * w + hq; if (pos > cnt - 1) pos = cnt - 1;
        int ni = ib[pos];
        {
            int posn = n0 + 64 + 16 * w + hq;
            if (posn > cnt - 1) posn = cnt - 1;
            LOAD_TILE(posn)
            PHASE_A_TAIL(n0, 0)
            ni = ni_next;
        }
        __syncthreads();

        for (int tb = n0 + 64; tb < n1; tb += 64) {
            int k = (tb - n0) >> 6;
            int cur = k & 1;
            int posn = tb + 64 + 16 * w + hq;
            if (posn > cnt - 1) posn = cnt - 1;
            LOAD_TILE(posn)

            PHASE_B(cur ^ 1)            // tile k-1, other buffer: hides load latency
            PHASE_A_TAIL(tb, cur)       // consumes this tile's loads

            ni = ni_next;
            lastk = k;
            __syncthreads();
        }

        PHASE_B(lastk & 1)              // trailing B of final tile
    }

    // ---- epilogue: bounce G through LDS for coalesced partial write ----
    __syncthreads();
    float* GL = (float*)smem;                      // [16][260] f32, reuses XT0
    #pragma unroll
    for (int r = 0; r < 4; ++r) {
        GL[hq * 260 + 64 * w +  0 + 4 * g + r] = accB0[r];
        GL[hq * 260 + 64 * w + 16 + 4 * g + r] = accB1[r];
        GL[hq * 260 + 64 * w + 32 + 4 * g + r] = accB2[r];
        GL[hq * 260 + 64 * w + 48 + 4 * g + r] = accB3[r];
    }
    if (lane < 16) LL[w * 16 + lane] = lacc;
    __syncthreads();

    float* rec = partials + (size_t)blockIdx.x * PREC2;
    if (t < NH) rec[t] = LL[t] + LL[16 + t] + LL[32 + t] + LL[48 + t];
    for (int i = t; i < NH * DIM; i += 256)
        rec[16 + i] = GL[(i >> 8) * 260 + (i & 255)];
}

// ---------------- kernel 3: merge partials + hc (fused) ---------------------
__global__ void reduce_hc_kernel(const float* __restrict__ partials,
                                 const float* __restrict__ Wv,
                                 float* __restrict__ hcws) {
    int b = blockIdx.x >> 4, h = blockIdx.x & 15;
    int t = threadIdx.x;
    __shared__ float grow[DIM];
    __shared__ float lp[NPART];
    __shared__ float lsum;

    const float* pb = partials + (size_t)b * NPART * PREC2;
    float a = 0.f;
    for (int p = 0; p < NPART; ++p) a += pb[(size_t)p * PREC2 + 16 + h * DIM + t];
    grow[t] = a;
    if (t < NPART) lp[t] = pb[(size_t)t * PREC2 + h];
    __syncthreads();
    if (t == 0) {
        float s = 0.f;
        #pragma unroll
        for (int p = 0; p < NPART; ++p) s += lp[p];
        lsum = s;
    }
    __syncthreads();

    int i = h * 16 + (t >> 4), sub = t & 15;
    const float4* wrow = (const float4*)(Wv + (size_t)i * DIM + sub * 16);
    const float4* gr = (const float4*)(grow + sub * 16);
    float s = 0.f;
    #pragma unroll
    for (int k = 0; k < 4; ++k) {
        float4 wv = wrow[k], gv = gr[k];
        s += wv.x * gv.x + wv.y * gv.y + wv.z * gv.z + wv.w * gv.w;
    }
    s += __shfl_xor(s, 1, 64);
    s += __shfl_xor(s, 2, 64);
    s += __shfl_xor(s, 4, 64);
    s += __shfl_xor(s, 8, 64);
    if (sub == 0) hcws[(size_t)b * DIM + i] = s / lsum;
}

// ---------------- kernel 4: out[b,e] = dot(hc[b,:], Wo[e,:]) ----------------
__global__ void out_kernel(const float* __restrict__ hcws,
                           const float* __restrict__ Wo,
                           float* __restrict__ out) {
    int b = blockIdx.x >> 3, o = blockIdx.x & 7;
    int t = threadIdx.x;
    int e = o * 32 + (t >> 3), sub = t & 7;
    const float4* wrow = (const float4*)(Wo + (size_t)e * DIM + sub * 32);
    const float4* hrow = (const float4*)(hcws + (size_t)b * DIM + sub * 32);
    float a = 0.f;
    #pragma unroll
    for (int k = 0; k < 8; ++k) {
        float4 wv = wrow[k], hv = hrow[k];
        a += wv.x * hv.x + wv.y * hv.y + wv.z * hv.z + wv.w * hv.w;
    }
    a += __shfl_xor(a, 1, 64);
    a += __shfl_xor(a, 2, 64);
    a += __shfl_xor(a, 4, 64);
    if (sub == 0) out[(size_t)b * DIM + e] = a;
}

extern "C" void kernel_launch(void* const* d_in, const int* in_sizes, int n_in,
                              void* d_out, int out_size, void* d_ws, size_t ws_size,
                              hipStream_t stream) {
    const float* ctx  = (const float*)d_in[0];
    const float* node = (const float*)d_in[1];
    const void*  mask = (const void*)d_in[2];
    const float* Wq   = (const float*)d_in[3];
    const float* Wk   = (const float*)d_in[4];
    const float* Wv   = (const float*)d_in[5];
    const float* Wo   = (const float*)d_in[6];
    float* out = (float*)d_out;

    // ws floats: wt 131072 | hcws 8192 | cnt 256 | idx 32*10240 |
    //            partials 32*16*4112 (~8.4MB)
    float* wsf = (float*)d_ws;
    float* wt = wsf;
    float* hcws = wt + (size_t)NB * NH * DIM;
    int*   cnt = (int*)(hcws + (size_t)NB * DIM);
    int*   idx = cnt + 256;
    float* partials = (float*)(idx + (size_t)NB * IDXSTRIDE);

    prep_compact_kernel<<<NB * 4 + NB, 256, 0, stream>>>(ctx, Wq, Wk, mask, wt, idx, cnt);
    attend_kernel<<<NB * NPART, 256, 0, stream>>>(node, idx, cnt, wt, partials);
    reduce_hc_kernel<<<NB * 16, 256, 0, stream>>>(partials, Wv, hcws);
    out_kernel<<<NB * 8, 256, 0, stream>>>(hcws, Wo, out);
}

// Round 16
// 70.682 us; speedup vs baseline: 1.1237x; 1.0235x over previous
//
#include <hip/hip_runtime.h>
#include <math.h>

#define NB 32
#define NN 10000
#define DIM 256
#define NH 16
#define NPART 16          // 32*16 = 512 blocks = exactly 2/CU at 2 blk/CU
#define PREC2 4112        // per-block partial: l[16] + g[16*256]
#define IDXSTRIDE 10240

typedef short short8v __attribute__((ext_vector_type(8)));
typedef float float4v __attribute__((ext_vector_type(4)));

// ---- bf16 helpers (RNE pack) ----
__device__ __forceinline__ unsigned bf16rne(float f) {
    unsigned u = __float_as_uint(f);
    return (u + 0x7FFFu + ((u >> 16) & 1u)) >> 16;
}
__device__ __forceinline__ unsigned pack2(float a, float b) {
    return bf16rne(a) | (bf16rne(b) << 16);
}
__device__ __forceinline__ short8v pack8(float4 A, float4 B) {
    union { short8v s; unsigned u[4]; } r;
    r.u[0] = pack2(A.x, A.y); r.u[1] = pack2(A.z, A.w);
    r.u[2] = pack2(B.x, B.y); r.u[3] = pack2(B.z, B.w);
    return r.s;
}
// row-parity XOR swizzle for XT (128B rows)
#define SWB(d) ((((d) >> 1) & 7) << 4)

// Raw barrier: waits LDS ops only, does NOT drain vmcnt (prefetched global
// loads stay in flight across it). sched_barrier(0) pins ordering; no
// "memory" clobber (round-8 lesson: that forces registers to scratch).
__device__ __forceinline__ void barrier_keep_vmcnt() {
    __builtin_amdgcn_sched_barrier(0);
    asm volatile("s_waitcnt lgkmcnt(0)");
    __builtin_amdgcn_s_barrier();
    __builtin_amdgcn_sched_barrier(0);
}

// ---------------- kernel 1: prep (blocks 0..127) + compact (128..159) -------
__global__ void prep_compact_kernel(const float* __restrict__ ctx,
                                    const float* __restrict__ Wq,
                                    const float* __restrict__ Wk,
                                    const void* __restrict__ maskp,
                                    float* __restrict__ wt,
                                    int* __restrict__ idx,
                                    int* __restrict__ cnt) {
    int bid = blockIdx.x;
    int t = threadIdx.x, lane = t & 63, w = t >> 6;

    __shared__ float ctxL[DIM];
    __shared__ float qL[64];
    __shared__ int sflag;
    __shared__ int wcnt[4];

    if (bid < 4 * NB) {
        // ---------------- prep: q then w~ ----------------
        int b = bid >> 2, iq = bid & 3;
        ctxL[t] = ctx[b * DIM + t];
        __syncthreads();

        float4 c = ((const float4*)ctxL)[lane];
        for (int i = iq * 64 + w; i < iq * 64 + 64; i += 4) {
            float4 wq = ((const float4*)(Wq + (size_t)i * DIM))[lane];
            float s = wq.x * c.x + wq.y * c.y + wq.z * c.z + wq.w * c.w;
            #pragma unroll
            for (int off = 1; off < 64; off <<= 1) s += __shfl_xor(s, off, 64);
            if (lane == 0) qL[i - iq * 64] = s;
        }
        __syncthreads();

        #pragma unroll
        for (int hh = 0; hh < 4; ++hh) {
            int h = iq * 4 + hh;
            float a = 0.f;
            #pragma unroll
            for (int j = 0; j < 16; ++j)
                a += qL[hh * 16 + j] * Wk[(size_t)(h * 16 + j) * DIM + t];
            wt[((size_t)b * NH + h) * DIM + t] = 0.25f * a;
        }
    } else {
        // ---------------- compact (stable, per-wave segments) --------------
        int b = bid - 4 * NB;
        const int* wordbase = (const int*)maskp + (size_t)b * (NN / 4);
        int bad = 0;
        for (int i = t; i < NN / 4; i += 256)
            if ((unsigned)wordbase[i] > 1u) bad = 1;
        if (t == 0) sflag = 0;
        __syncthreads();
        if (bad) sflag = 1;            // benign race: same value
        __syncthreads();
        const bool bytemask = (sflag != 0);
        const unsigned char* m8 = (const unsigned char*)maskp + (size_t)b * NN;
        const int* m32 = (const int*)maskp + (size_t)b * NN;

        int segbeg = w * (NN / 4);
        int segend = segbeg + (NN / 4);

        int c1 = 0;
        for (int base = segbeg; base < segend; base += 64) {
            int i = base + lane;
            int pred = (i < segend) ? (bytemask ? (m8[i] != 0) : (m32[i] != 0)) : 0;
            unsigned long long bal = __ballot(pred);
            c1 += __popcll(bal);
        }
        if (lane == 0) wcnt[w] = c1;
        __syncthreads();

        int run = 0;
        for (int k = 0; k < w; ++k) run += wcnt[k];

        int* ob = idx + (size_t)b * IDXSTRIDE;
        for (int base = segbeg; base < segend; base += 64) {
            int i = base + lane;
            int pred = (i < segend) ? (bytemask ? (m8[i] != 0) : (m32[i] != 0)) : 0;
            unsigned long long bal = __ballot(pred);
            int rank = __popcll(bal & ((1ull << lane) - 1ull));
            if (pred) ob[run + rank] = i;
            run += __popcll(bal);
        }
        if (t == 0) cnt[b] = wcnt[0] + wcnt[1] + wcnt[2] + wcnt[3];
    }
}

// ---- file-scope macro pieces for the attend kernel (expand at use site) ----
// Buffer addresses computed arithmetically from smem (no pointer arrays).
#define XTBUF(bb) (smem + (size_t)(bb) * 32768)
#define PLBUF(bb) (smem + 65536 + (size_t)(bb) * 2304)

// STEP_A: pack one 8-dword chunk, scatter into XTc, MFMA into acc.
#define STEP_A(cc) { \
    short8v af = pack8(LA##cc, LB##cc); \
    union { short8v s; unsigned short u[8]; } U; U.s = af; \
    int d0 = g * 8 + cc * 32; \
    _Pragma("unroll") \
    for (int j = 0; j < 8; ++j) \
        *(unsigned short*)(XTc + (size_t)(d0 + j) * 128 + \
                           (ln2 ^ SWB(d0 + j))) = U.u[j]; \
    acc = __builtin_amdgcn_mfma_f32_16x16x32_bf16(af, wfrag##cc, acc, 0, 0, 0); \
}

// PHASE_A_TAIL: full phase A for tile at tb_ into buffer cur_ (consumes LA/LB).
#define PHASE_A_TAIL(tb_, cur_) { \
    char* XTc = XTBUF(cur_); char* PLc = PLBUF(cur_); \
    float4v acc = (float4v){0.f, 0.f, 0.f, 0.f}; \
    STEP_A(0) STEP_A(1) STEP_A(2) STEP_A(3) \
    STEP_A(4) STEP_A(5) STEP_A(6) STEP_A(7) \
    int mb_ = (tb_) + 16 * w + 4 * g; \
    float p0 = (mb_ + 0 < n1) ? __expf(acc[0]) : 0.f; \
    float p1 = (mb_ + 1 < n1) ? __expf(acc[1]) : 0.f; \
    float p2 = (mb_ + 2 < n1) ? __expf(acc[2]) : 0.f; \
    float p3 = (mb_ + 3 < n1) ? __expf(acc[3]) : 0.f; \
    float ts = p0 + p1 + p2 + p3; \
    ts += __shfl_xor(ts, 16, 64); \
    ts += __shfl_xor(ts, 32, 64); \
    lacc += ts; \
    *(uint2*)(PLc + hq * 144 + (16 * w + 4 * g) * 2) = \
        make_uint2(pack2(p0, p1), pack2(p2, p3)); \
}

// PHASE_B: 8 MFMA + 10 ds_read_b128 consuming buffer bb.
#define PHASE_B(bb) { \
    char* XTp = XTBUF(bb); char* PLp = PLBUF(bb); \
    _Pragma("unroll") \
    for (int chunk = 0; chunk < 2; ++chunk) { \
        short8v pf = *(const short8v*)(PLp + hq * 144 + chunk * 64 + g * 16); \
        int d0 = 64 * w + hq; \
        short8v xf0 = *(const short8v*)(XTp + (size_t)(d0) * 128 + \
                                        ((chunk * 64 + g * 16) ^ SWB(d0))); \
        short8v xf1 = *(const short8v*)(XTp + (size_t)(d0 + 16) * 128 + \
                                        ((chunk * 64 + g * 16) ^ SWB(d0 + 16))); \
        short8v xf2 = *(const short8v*)(XTp + (size_t)(d0 + 32) * 128 + \
                                        ((chunk * 64 + g * 16) ^ SWB(d0 + 32))); \
        short8v xf3 = *(const short8v*)(XTp + (size_t)(d0 + 48) * 128 + \
                                        ((chunk * 64 + g * 16) ^ SWB(d0 + 48))); \
        accB0 = __builtin_amdgcn_mfma_f32_16x16x32_bf16(xf0, pf, accB0, 0, 0, 0); \
        accB1 = __builtin_amdgcn_mfma_f32_16x16x32_bf16(xf1, pf, accB1, 0, 0, 0); \
        accB2 = __builtin_amdgcn_mfma_f32_16x16x32_bf16(xf2, pf, accB2, 0, 0, 0); \
        accB3 = __builtin_amdgcn_mfma_f32_16x16x32_bf16(xf3, pf, accB3, 0, 0, 0); \
    } \
}

// LOAD_TILE: issue 16 row loads (row = ni) into the kernel-scope LA/LB regs,
// prefetch next idx into ni. Pin all 17 VMEM reads to issue first.
#define LOAD_TILE(nextpos_) { \
    const float* arow = nb + (size_t)ni * DIM + g * 8; \
    LA0 = *(const float4*)(arow + 0);   LB0 = *(const float4*)(arow + 4); \
    LA1 = *(const float4*)(arow + 32);  LB1 = *(const float4*)(arow + 36); \
    LA2 = *(const float4*)(arow + 64);  LB2 = *(const float4*)(arow + 68); \
    LA3 = *(const float4*)(arow + 96);  LB3 = *(const float4*)(arow + 100); \
    LA4 = *(const float4*)(arow + 128); LB4 = *(const float4*)(arow + 132); \
    LA5 = *(const float4*)(arow + 160); LB5 = *(const float4*)(arow + 164); \
    LA6 = *(const float4*)(arow + 192); LB6 = *(const float4*)(arow + 196); \
    LA7 = *(const float4*)(arow + 224); LB7 = *(const float4*)(arow + 228); \
    ni = ib[nextpos_]; \
    __builtin_amdgcn_sched_group_barrier(0x20, 17, 0); \
}

#define CLAMPPOS(base_) ((base_) + 16 * w + hq > cnt - 1 ? cnt - 1 : (base_) + 16 * w + hq)

// ---------------- kernel 2: MFMA attend, cross-barrier prefetch -------------
// Loads for tile k+1 are issued at the END of iteration k and consumed by
// PHASE_A at iteration k+1 — in flight across exactly ONE raw barrier
// (vmcnt preserved). Latency cover = barrier + PHASE_B + A-pack (~full iter).
// At __launch_bounds__(256,2) the 64-VGPR prefetch fits without spill.
__launch_bounds__(256, 2)
__global__ void attend_kernel(const float* __restrict__ node,
                              const int* __restrict__ idx,
                              const int* __restrict__ cntarr,
                              const float* __restrict__ wt,
                              float* __restrict__ partials) {
    __shared__ __align__(16) char smem[70400];
    // layout: XT0 32768 | XT1 32768 | PL0 2304 | PL1 2304 | LL 256
    float* LL = (float*)(smem + 70144);

    int b = blockIdx.x / NPART;
    int part = blockIdx.x % NPART;
    int t = threadIdx.x, lane = t & 63;
    int w = __builtin_amdgcn_readfirstlane(t >> 6);
    int hq = lane & 15, g = lane >> 4;

    int cnt = cntarr[b];
    int psz = ((cnt + NPART * 64 - 1) / (NPART * 64)) * 64;  // tile-aligned
    int n0 = part * psz;
    int n1 = n0 + psz; if (n1 > cnt) n1 = cnt;

    const float* nb = node + (size_t)b * NN * DIM;
    const int* ib = idx + (size_t)b * IDXSTRIDE;

    // hoist w~ B-fragments (once per block; same for all waves)
    short8v wfrag0, wfrag1, wfrag2, wfrag3, wfrag4, wfrag5, wfrag6, wfrag7;
    {
        const float* wrow = wt + ((size_t)b * NH + hq) * DIM + g * 8;
        #define WLOAD(cc) wfrag##cc = pack8(*(const float4*)(wrow + cc * 32), \
                                            *(const float4*)(wrow + cc * 32 + 4));
        WLOAD(0) WLOAD(1) WLOAD(2) WLOAD(3) WLOAD(4) WLOAD(5) WLOAD(6) WLOAD(7)
        #undef WLOAD
    }

    float4v accB0 = (float4v){0.f,0.f,0.f,0.f};
    float4v accB1 = accB0, accB2 = accB0, accB3 = accB0;
    float lacc = 0.f;
    int ln2 = (16 * w + hq) * 2;   // XT byte-column of this lane's node slot

    // prefetch registers (kernel scope: live across one raw barrier)
    float4 LA0, LA1, LA2, LA3, LA4, LA5, LA6, LA7;
    float4 LB0, LB1, LB2, LB3, LB4, LB5, LB6, LB7;
    int ni;

    if (n0 < n1) {
        int nt = (n1 - n0 + 63) >> 6;

        // prologue: tile0 regs -> A(0); then preload tile1 regs
        ni = ib[CLAMPPOS(n0)];
        LOAD_TILE(CLAMPPOS(n0 + 64))          // loads tile0; ni <- idx(tile1)
        PHASE_A_TAIL(n0, 0)
        if (nt > 1) {
            LOAD_TILE(CLAMPPOS(n0 + 128))     // loads tile1; ni <- idx(tile2)
        }
        barrier_keep_vmcnt();

        for (int tb = n0 + 64; tb < n1; tb += 64) {
            int k = (tb - n0) >> 6;
            int cur = k & 1;
            PHASE_B(cur ^ 1)                  // tile k-1 from other buffer
            PHASE_A_TAIL(tb, cur)             // consumes tile-k regs (prefetched)
            if (tb + 64 < n1) {
                LOAD_TILE(CLAMPPOS(tb + 128)) // issue tile k+1; flies over barrier
            }
            barrier_keep_vmcnt();
        }

        PHASE_B((nt - 1) & 1)                 // trailing B of final tile
    }

    // ---- epilogue: bounce G through LDS for coalesced partial write ----
    __syncthreads();
    float* GL = (float*)smem;                      // [16][260] f32, reuses XT0
    #pragma unroll
    for (int r = 0; r < 4; ++r) {
        GL[hq * 260 + 64 * w +  0 + 4 * g + r] = accB0[r];
        GL[hq * 260 + 64 * w + 16 + 4 * g + r] = accB1[r];
        GL[hq * 260 + 64 * w + 32 + 4 * g + r] = accB2[r];
        GL[hq * 260 + 64 * w + 48 + 4 * g + r] = accB3[r];
    }
    if (lane < 16) LL[w * 16 + lane] = lacc;
    __syncthreads();

    float* rec = partials + (size_t)blockIdx.x * PREC2;
    if (t < NH) rec[t] = LL[t] + LL[16 + t] + LL[32 + t] + LL[48 + t];
    for (int i = t; i < NH * DIM; i += 256)
        rec[16 + i] = GL[(i >> 8) * 260 + (i & 255)];
}

// ---------------- kernel 3: merge partials + hc (fused) ---------------------
__global__ void reduce_hc_kernel(const float* __restrict__ partials,
                                 const float* __restrict__ Wv,
                                 float* __restrict__ hcws) {
    int b = blockIdx.x >> 4, h = blockIdx.x & 15;
    int t = threadIdx.x;
    __shared__ float grow[DIM];
    __shared__ float lp[NPART];
    __shared__ float lsum;

    const float* pb = partials + (size_t)b * NPART * PREC2;
    float a = 0.f;
    for (int p = 0; p < NPART; ++p) a += pb[(size_t)p * PREC2 + 16 + h * DIM + t];
    grow[t] = a;
    if (t < NPART) lp[t] = pb[(size_t)t * PREC2 + h];
    __syncthreads();
    if (t == 0) {
        float s = 0.f;
        #pragma unroll
        for (int p = 0; p < NPART; ++p) s += lp[p];
        lsum = s;
    }
    __syncthreads();

    int i = h * 16 + (t >> 4), sub = t & 15;
    const float4* wrow = (const float4*)(Wv + (size_t)i * DIM + sub * 16);
    const float4* gr = (const float4*)(grow + sub * 16);
    float s = 0.f;
    #pragma unroll
    for (int k = 0; k < 4; ++k) {
        float4 wv = wrow[k], gv = gr[k];
        s += wv.x * gv.x + wv.y * gv.y + wv.z * gv.z + wv.w * gv.w;
    }
    s += __shfl_xor(s, 1, 64);
    s += __shfl_xor(s, 2, 64);
    s += __shfl_xor(s, 4, 64);
    s += __shfl_xor(s, 8, 64);
    if (sub == 0) hcws[(size_t)b * DIM + i] = s / lsum;
}

// ---------------- kernel 4: out[b,e] = dot(hc[b,:], Wo[e,:]) ----------------
__global__ void out_kernel(const float* __restrict__ hcws,
                           const float* __restrict__ Wo,
                           float* __restrict__ out) {
    int b = blockIdx.x >> 3, o = blockIdx.x & 7;
    int t = threadIdx.x;
    int e = o * 32 + (t >> 3), sub = t & 7;
    const float4* wrow = (const float4*)(Wo + (size_t)e * DIM + sub * 32);
    const float4* hrow = (const float4*)(hcws + (size_t)b * DIM + sub * 32);
    float a = 0.f;
    #pragma unroll
    for (int k = 0; k < 8; ++k) {
        float4 wv = wrow[k], hv = hrow[k];
        a += wv.x * hv.x + wv.y * hv.y + wv.z * hv.z + wv.w * hv.w;
    }
    a += __shfl_xor(a, 1, 64);
    a += __shfl_xor(a, 2, 64);
    a += __shfl_xor(a, 4, 64);
    if (sub == 0) out[(size_t)b * DIM + e] = a;
}

extern "C" void kernel_launch(void* const* d_in, const int* in_sizes, int n_in,
                              void* d_out, int out_size, void* d_ws, size_t ws_size,
                              hipStream_t stream) {
    const float* ctx  = (const float*)d_in[0];
    const float* node = (const float*)d_in[1];
    const void*  mask = (const void*)d_in[2];
    const float* Wq   = (const float*)d_in[3];
    const float* Wk   = (const float*)d_in[4];
    const float* Wv   = (const float*)d_in[5];
    const float* Wo   = (const float*)d_in[6];
    float* out = (float*)d_out;

    // ws floats: wt 131072 | hcws 8192 | cnt 256 | idx 32*10240 |
    //            partials 32*16*4112 (~8.4MB)
    float* wsf = (float*)d_ws;
    float* wt = wsf;
    float* hcws = wt + (size_t)NB * NH * DIM;
    int*   cnt = (int*)(hcws + (size_t)NB * DIM);
    int*   idx = cnt + 256;
    float* partials = (float*)(idx + (size_t)NB * IDXSTRIDE);

    prep_compact_kernel<<<NB * 4 + NB, 256, 0, stream>>>(ctx, Wq, Wk, mask, wt, idx, cnt);
    attend_kernel<<<NB * NPART, 256, 0, stream>>>(node, idx, cnt, wt, partials);
    reduce_hc_kernel<<<NB * 16, 256, 0, stream>>>(partials, Wv, hcws);
    out_kernel<<<NB * 8, 256, 0, stream>>>(hcws, Wo, out);
}